// Round 3
// baseline (237.959 us; speedup 1.0000x reference)
//
#include <hip/hip_runtime.h>
#include <math.h>

// RX(theta) on qubit 5 of 12, batch 4096 x dim 4096, fp32.
// out_re[i] = c*sr[i] + s*si[i^64];  out_im[i] = c*si[i] - s*sr[i^64]
// c = cos(theta/2), s = sin(theta/2).  Pure streaming butterfly.
//
// Structure mimics the known 6.3 TB/s copy: few persistent blocks, each
// thread owns 4 pairs (256B loads all independent & issued before any use),
// no shuffle/LDS, plain loads + nontemporal stores.

#define NQ_N 4096
#define NQ_BATCH 4096
#define TOTAL_VECS   ((unsigned)((size_t)NQ_BATCH * NQ_N / 4))  // 2^22 float4s
#define TOTAL_PAIRS  (TOTAL_VECS / 2)                           // 2^21
#define UNROLL 4
#define BLOCK 256
#define GRID  (TOTAL_PAIRS / (BLOCK * UNROLL))                  // 2048 blocks
#define THREADS_TOTAL (GRID * BLOCK)                            // 2^19

typedef float f32x4 __attribute__((ext_vector_type(4)));

__global__ __launch_bounds__(BLOCK, 4)
void rx_butterfly_kernel(const f32x4* __restrict__ sr,
                         const f32x4* __restrict__ si,
                         const float* __restrict__ theta_p,
                         f32x4* __restrict__ out_re,
                         f32x4* __restrict__ out_im)
{
    const float half = 0.5f * theta_p[0];
    const float c = cosf(half);
    const float s = sinf(half);

    const unsigned tid = blockIdx.x * BLOCK + threadIdx.x;

    unsigned v[UNROLL], w[UNROLL];
    f32x4 srL[UNROLL], srH[UNROLL], siL[UNROLL], siH[UNROLL];

    // Issue all 16 loads back-to-back: 256B in flight per thread.
#pragma unroll
    for (int u = 0; u < UNROLL; ++u) {
        const unsigned p = tid + (unsigned)u * THREADS_TOTAL; // pair index
        v[u] = ((p >> 4) << 5) | (p & 15u);  // insert 0 at bit 4
        w[u] = v[u] | 16u;                   // partner float4 (i ^ 64)
        srL[u] = sr[v[u]];
        srH[u] = sr[w[u]];
        siL[u] = si[v[u]];
        siH[u] = si[w[u]];
    }

#pragma unroll
    for (int u = 0; u < UNROLL; ++u) {
        const f32x4 reL = c * srL[u] + s * siH[u];
        const f32x4 reH = c * srH[u] + s * siL[u];
        const f32x4 imL = c * siL[u] - s * srH[u];
        const f32x4 imH = c * siH[u] - s * srL[u];
        __builtin_nontemporal_store(reL, out_re + v[u]);
        __builtin_nontemporal_store(reH, out_re + w[u]);
        __builtin_nontemporal_store(imL, out_im + v[u]);
        __builtin_nontemporal_store(imH, out_im + w[u]);
    }
}

extern "C" void kernel_launch(void* const* d_in, const int* in_sizes, int n_in,
                              void* d_out, int out_size, void* d_ws, size_t ws_size,
                              hipStream_t stream)
{
    const f32x4* sr = (const f32x4*)d_in[0];
    const f32x4* si = (const f32x4*)d_in[1];
    const float* th = (const float*)d_in[2];

    f32x4* out_re = (f32x4*)d_out;
    f32x4* out_im = out_re + TOTAL_VECS;

    rx_butterfly_kernel<<<GRID, BLOCK, 0, stream>>>(sr, si, th, out_re, out_im);
}